// Round 3
// baseline (242.439 us; speedup 1.0000x reference)
//
#include <hip/hip_runtime.h>
#include <hip/hip_bf16.h>
#include <math.h>

#define NQ 196
#define BATCH 4
#define HD 512            // H * D_K == D_MODEL
#define NH 8
#define DK 64
#define MROWS 784         // BATCH*NQ

typedef __attribute__((ext_vector_type(8))) short short8;
typedef __attribute__((ext_vector_type(4))) float float4v;

// ---------------- split: fp32 -> bf16 hi/lo pair ----------------
// 7 segments: queries/keys/values (196 blocks each), Wq/Wk/Wv/Wo (128 each).
// Each block converts 2048 contiguous elements (8 per thread).
struct SplitArgs {
  const float* src[7];
  __hip_bfloat16* hi[7];
  __hip_bfloat16* lo[7];
};

__global__ __launch_bounds__(256)
void split_kernel(SplitArgs a) {
  const int blk = blockIdx.x;
  int seg, base;
  if (blk < 588) { seg = blk / 196; base = seg * 196; }
  else           { seg = 3 + (blk - 588) / 128; base = 588 + (seg - 3) * 128; }
  const size_t off = (size_t)(blk - base) * 2048 + (size_t)threadIdx.x * 8;
  const float* src = a.src[seg] + off;
  float4 v0 = *(const float4*)(src);
  float4 v1 = *(const float4*)(src + 4);
  float x[8] = {v0.x, v0.y, v0.z, v0.w, v1.x, v1.y, v1.z, v1.w};
  short hh[8], ll[8];
  #pragma unroll
  for (int i = 0; i < 8; ++i) {
    __hip_bfloat16 bh = __float2bfloat16(x[i]);
    float xh = __bfloat162float(bh);
    __hip_bfloat16 bl = __float2bfloat16(x[i] - xh);
    hh[i] = __builtin_bit_cast(short, bh);
    ll[i] = __builtin_bit_cast(short, bl);
  }
  short8 vh = {hh[0],hh[1],hh[2],hh[3],hh[4],hh[5],hh[6],hh[7]};
  short8 vl = {ll[0],ll[1],ll[2],ll[3],ll[4],ll[5],ll[6],ll[7]};
  *(short8*)((short*)a.hi[seg] + off) = vh;
  *(short8*)((short*)a.lo[seg] + off) = vl;
}

// ---------------- bf16x3-split MFMA GEMM: C = X @ W^T + bias ----------------
// X:(M,K) row-major split (Ah,Al), W:(N,K) row-major split (Bh,Bl), C fp32.
// Block 256 thr = 4 waves; block tile 16(M) x 128(N); wave: two 16x16 n-tiles.
// Optional epilogue: c = sigmoid(gate*c)*c.
struct GemmPtrs {
  const __hip_bfloat16* Ah[3]; const __hip_bfloat16* Al[3];
  const __hip_bfloat16* Bh[3]; const __hip_bfloat16* Bl[3];
  const float* bias[3]; float* C[3];
};

__global__ __launch_bounds__(256)
void mfma_gemm(GemmPtrs p, const float* __restrict__ gate, int M, int N, int K) {
  const int z = blockIdx.z;
  const short* __restrict__ Ah = (const short*)p.Ah[z];
  const short* __restrict__ Al = (const short*)p.Al[z];
  const short* __restrict__ Bh = (const short*)p.Bh[z];
  const short* __restrict__ Bl = (const short*)p.Bl[z];
  const float* __restrict__ bias = p.bias[z];
  float* __restrict__ C = p.C[z];

  const int m0 = blockIdx.x * 16;
  const int n0 = blockIdx.y * 128;
  const int w  = threadIdx.x >> 6;
  const int ln = threadIdx.x & 63;
  const int lm = ln & 15;          // A row / B row / D col
  const int quad = ln >> 4;        // k-group for A/B, row-group for D

  const int nA = n0 + w * 32;      // wave's two n-tiles: nA, nA+16
  float4v acc0 = {0.f, 0.f, 0.f, 0.f};
  float4v acc1 = {0.f, 0.f, 0.f, 0.f};

  const size_t arow  = (size_t)(m0 + lm) * K + quad * 8;
  const size_t brow0 = (size_t)(nA + lm) * K + quad * 8;
  const size_t brow1 = (size_t)(nA + 16 + lm) * K + quad * 8;

  for (int k0 = 0; k0 < K; k0 += 32) {
    short8 ah  = *(const short8*)(Ah + arow  + k0);
    short8 al  = *(const short8*)(Al + arow  + k0);
    short8 bh0 = *(const short8*)(Bh + brow0 + k0);
    short8 bl0 = *(const short8*)(Bl + brow0 + k0);
    short8 bh1 = *(const short8*)(Bh + brow1 + k0);
    short8 bl1 = *(const short8*)(Bl + brow1 + k0);
    acc0 = __builtin_amdgcn_mfma_f32_16x16x32_bf16(ah, bh0, acc0, 0, 0, 0);
    acc1 = __builtin_amdgcn_mfma_f32_16x16x32_bf16(ah, bh1, acc1, 0, 0, 0);
    acc0 = __builtin_amdgcn_mfma_f32_16x16x32_bf16(ah, bl0, acc0, 0, 0, 0);
    acc1 = __builtin_amdgcn_mfma_f32_16x16x32_bf16(ah, bl1, acc1, 0, 0, 0);
    acc0 = __builtin_amdgcn_mfma_f32_16x16x32_bf16(al, bh0, acc0, 0, 0, 0);
    acc1 = __builtin_amdgcn_mfma_f32_16x16x32_bf16(al, bh1, acc1, 0, 0, 0);
  }

  #pragma unroll
  for (int nt = 0; nt < 2; ++nt) {
    float4v acc = nt ? acc1 : acc0;
    const int n = (nt ? nA + 16 : nA) + lm;
    const float bv = bias[n];
    #pragma unroll
    for (int r = 0; r < 4; ++r) {
      const int m = m0 + quad * 4 + r;
      float c = acc[r] + bv;
      if (gate) {
        float qg = gate[(size_t)m * N + n];
        c = __fdividef(c, 1.f + __expf(-qg * c));  // sigmoid(qg*c)*c
      }
      C[(size_t)m * N + n] = c;
    }
  }
}

// ---------------- scores + softmax -> pbuf ----------------
__global__ __launch_bounds__(256)
void scores_kernel(const float* __restrict__ qsg, const float* __restrict__ kpg,
                   const float* __restrict__ scg, float* __restrict__ pbuf) {
  const int b  = blockIdx.z;
  const int h  = blockIdx.y;
  const int q0 = blockIdx.x * 14;
  const int t  = threadIdx.x;

  __shared__ float klds[NQ * 65];
  __shared__ float qlds[14 * 64];
  __shared__ float red[8];

  const float* kp = kpg + (size_t)b * NQ * HD + h * DK;
  for (int idx = t; idx < NQ * 16; idx += 256) {
    int r = idx >> 4, j = (idx & 15) << 2;
    float4 v = *(const float4*)(kp + (size_t)r * HD + j);
    float* d = &klds[r * 65 + j];
    d[0] = v.x; d[1] = v.y; d[2] = v.z; d[3] = v.w;
  }
  const float* qp = qsg + ((size_t)b * NQ + q0) * HD + h * DK;
  for (int idx = t; idx < 14 * 16; idx += 256) {
    int r = idx >> 4, j = (idx & 15) << 2;
    float4 v = *(const float4*)(qp + (size_t)r * HD + j);
    float* d = &qlds[r * 64 + j];
    d[0] = v.x; d[1] = v.y; d[2] = v.z; d[3] = v.w;
  }
  __syncthreads();

  for (int qi = 0; qi < 14; ++qi) {
    const int q = q0 + qi;
    float att = -1e30f;
    if (t < NQ) {
      const float* kr = &klds[t * 65];
      const float* qr = &qlds[qi * 64];
      float dot = 0.f;
      #pragma unroll 16
      for (int d = 0; d < DK; ++d) dot += qr[d] * kr[d];
      att = dot * scg[((size_t)h * NQ + q) * NQ + t];
    }
    float m = att;
    #pragma unroll
    for (int off = 32; off; off >>= 1) m = fmaxf(m, __shfl_xor(m, off, 64));
    if ((t & 63) == 0) red[t >> 6] = m;
    __syncthreads();
    m = fmaxf(fmaxf(red[0], red[1]), fmaxf(red[2], red[3]));
    const float e = (t < NQ) ? __expf(att - m) : 0.f;
    float s = e;
    #pragma unroll
    for (int off = 32; off; off >>= 1) s += __shfl_xor(s, off, 64);
    __syncthreads();
    if ((t & 63) == 0) red[t >> 6] = s;
    __syncthreads();
    s = red[0] + red[1] + red[2] + red[3];
    const float rinv = __fdividef(1.f, s);
    if (t < NQ)
      pbuf[(((size_t)(b * NH + h) * NQ) + q) * NQ + t] = e * rinv;
    __syncthreads();
  }
}

// ---------------- gated PV: QB=4 q-blocking, emits bf16-split image ----------
__global__ __launch_bounds__(512)
void pv_kernel(const float* __restrict__ qsg, const float* __restrict__ kpg,
               const float* __restrict__ vpg, const float* __restrict__ pbuf,
               __hip_bfloat16* __restrict__ imgh, __hip_bfloat16* __restrict__ imgl) {
  const int b  = blockIdx.y;
  const int q0 = blockIdx.x * 4;
  const int hd = threadIdx.x;
  const int h  = hd >> 6;

  const size_t rowq = (size_t)(b * NQ + q0) * HD + hd;
  const float LOG2E = 1.4426950408889634f;
  float nqs[4];
  #pragma unroll
  for (int qi = 0; qi < 4; ++qi)
    nqs[qi] = -qsg[rowq + (size_t)qi * HD] * LOG2E;

  const float* kp = kpg + (size_t)b * NQ * HD + hd;
  const float* vp = vpg + (size_t)b * NQ * HD + hd;
  const float* pr = pbuf + ((size_t)(b * NH + h) * NQ + q0) * NQ;

  float acc[4] = {0.f, 0.f, 0.f, 0.f};
  #pragma unroll 2
  for (int k = 0; k < NQ; ++k) {
    float kv = kp[(size_t)k * HD];
    float vv = vp[(size_t)k * HD];
    #pragma unroll
    for (int qi = 0; qi < 4; ++qi) {
      float e = exp2f(nqs[qi] * kv);                 // e^(-qs*kv)
      float g = __fdividef(vv, 1.f + e);             // sigmoid(qs*kv)*vv
      acc[qi] += pr[(size_t)qi * NQ + k] * g;
    }
  }
  #pragma unroll
  for (int qi = 0; qi < 4; ++qi) {
    float x = acc[qi];
    __hip_bfloat16 xh = __float2bfloat16(x);
    float xhf = __bfloat162float(xh);
    imgh[rowq + (size_t)qi * HD] = xh;
    imgl[rowq + (size_t)qi * HD] = __float2bfloat16(x - xhf);
  }
}

extern "C" void kernel_launch(void* const* d_in, const int* in_sizes, int n_in,
                              void* d_out, int out_size, void* d_ws, size_t ws_size,
                              hipStream_t stream) {
  const float* queries = (const float*)d_in[0];
  const float* keys    = (const float*)d_in[1];
  const float* values  = (const float*)d_in[2];
  const float* Wq = (const float*)d_in[3];
  const float* bq = (const float*)d_in[4];
  const float* Wk = (const float*)d_in[5];
  const float* bk = (const float*)d_in[6];
  const float* Wv = (const float*)d_in[7];
  const float* bv = (const float*)d_in[8];
  const float* Wo = (const float*)d_in[9];
  const float* bo = (const float*)d_in[10];
  const float* scale = (const float*)d_in[11];

  const size_t NEL = (size_t)MROWS * HD;    // 401408
  const size_t WEL = (size_t)HD * HD;       // 262144

  float* ws = (float*)d_ws;
  float* q_sig = ws;
  float* k_p   = ws + NEL;
  float* v_p   = ws + 2 * NEL;
  float* pbuf  = ws + 3 * NEL;              // 4*8*196*196 = 1229312 floats
  __hip_bfloat16* bfbase = (__hip_bfloat16*)(ws + 3 * NEL + (size_t)BATCH * NH * NQ * NQ);
  __hip_bfloat16* qh = bfbase;              __hip_bfloat16* ql = qh + NEL;
  __hip_bfloat16* kh = ql + NEL;            __hip_bfloat16* kl = kh + NEL;
  __hip_bfloat16* vh = kl + NEL;            __hip_bfloat16* vl = vh + NEL;
  __hip_bfloat16* Wqh = vl + NEL;           __hip_bfloat16* Wql = Wqh + WEL;
  __hip_bfloat16* Wkh = Wql + WEL;          __hip_bfloat16* Wkl = Wkh + WEL;
  __hip_bfloat16* Wvh = Wkl + WEL;          __hip_bfloat16* Wvl = Wvh + WEL;
  __hip_bfloat16* Woh = Wvl + WEL;          __hip_bfloat16* Wol = Woh + WEL;
  __hip_bfloat16* imgh = Wol + WEL;         __hip_bfloat16* imgl = imgh + NEL;

  // 1) split inputs to bf16 hi/lo
  SplitArgs sa;
  sa.src[0] = queries; sa.hi[0] = qh;  sa.lo[0] = ql;
  sa.src[1] = keys;    sa.hi[1] = kh;  sa.lo[1] = kl;
  sa.src[2] = values;  sa.hi[2] = vh;  sa.lo[2] = vl;
  sa.src[3] = Wq;      sa.hi[3] = Wqh; sa.lo[3] = Wql;
  sa.src[4] = Wk;      sa.hi[4] = Wkh; sa.lo[4] = Wkl;
  sa.src[5] = Wv;      sa.hi[5] = Wvh; sa.lo[5] = Wvl;
  sa.src[6] = Wo;      sa.hi[6] = Woh; sa.lo[6] = Wol;
  split_kernel<<<1100, 256, 0, stream>>>(sa);

  // 2) projections via bf16x3 MFMA
  GemmPtrs gp;
  gp.Ah[0] = qh;  gp.Al[0] = ql;  gp.Bh[0] = Wqh; gp.Bl[0] = Wql; gp.bias[0] = bq; gp.C[0] = q_sig;
  gp.Ah[1] = kh;  gp.Al[1] = kl;  gp.Bh[1] = Wkh; gp.Bl[1] = Wkl; gp.bias[1] = bk; gp.C[1] = k_p;
  gp.Ah[2] = vh;  gp.Al[2] = vl;  gp.Bh[2] = Wvh; gp.Bl[2] = Wvl; gp.bias[2] = bv; gp.C[2] = v_p;
  mfma_gemm<<<dim3(MROWS / 16, HD / 128, 3), 256, 0, stream>>>(gp, nullptr, MROWS, HD, HD);

  // 3) scores + softmax
  scores_kernel<<<dim3(NQ / 14, NH, BATCH), 256, 0, stream>>>(q_sig, k_p, scale, pbuf);

  // 4) gated PV -> image (bf16 split)
  pv_kernel<<<dim3(NQ / 4, BATCH), 512, 0, stream>>>(q_sig, k_p, v_p, pbuf, imgh, imgl);

  // 5) out = image @ Wo^T + bo, gated by q_sig
  GemmPtrs go;
  for (int i = 0; i < 3; ++i) {
    go.Ah[i] = imgh; go.Al[i] = imgl; go.Bh[i] = Woh; go.Bl[i] = Wol;
    go.bias[i] = bo; go.C[i] = (float*)d_out;
  }
  mfma_gemm<<<dim3(MROWS / 16, HD / 128, 1), 256, 0, stream>>>(go, q_sig, MROWS, HD, HD);
}

// Round 4
// 191.229 us; speedup vs baseline: 1.2678x; 1.2678x over previous
//
#include <hip/hip_runtime.h>
#include <hip/hip_bf16.h>
#include <math.h>

#define NQ 196
#define BATCH 4
#define HD 512            // H * D_K == D_MODEL
#define NH 8
#define DK 64
#define MROWS 784         // BATCH*NQ
#define MPAD 832          // padded to 13*64 rows for unguarded tile staging

typedef __attribute__((ext_vector_type(8))) short short8;
typedef __attribute__((ext_vector_type(4))) float float4v;

__device__ __forceinline__ float b2f(short s) {
  return __uint_as_float(((unsigned)(unsigned short)s) << 16);
}
__device__ __forceinline__ short f2b(float x) {
  return __builtin_bit_cast(short, __float2bfloat16(x));
}

// ---------------- split: fp32 -> bf16 hi/lo pair ----------------
// segs 0..2: queries/keys/values (196 blocks each, 784x512);
// segs 3..6: Wq/Wk/Wv/Wo (128 blocks each, 512x512).
struct SplitArgs {
  const float* src[7];
  short* hi[7];
  short* lo[7];
};

__global__ __launch_bounds__(256)
void split_kernel(SplitArgs a) {
  const int blk = blockIdx.x;
  int seg, base;
  if (blk < 588) { seg = blk / 196; base = seg * 196; }
  else           { seg = 3 + (blk - 588) / 128; base = 588 + (seg - 3) * 128; }
  const size_t off = (size_t)(blk - base) * 2048 + (size_t)threadIdx.x * 8;
  const float* src = a.src[seg] + off;
  float4 v0 = *(const float4*)(src);
  float4 v1 = *(const float4*)(src + 4);
  float x[8] = {v0.x, v0.y, v0.z, v0.w, v1.x, v1.y, v1.z, v1.w};
  short hh[8], ll[8];
  #pragma unroll
  for (int i = 0; i < 8; ++i) {
    hh[i] = f2b(x[i]);
    ll[i] = f2b(x[i] - b2f(hh[i]));
  }
  short8 vh = {hh[0],hh[1],hh[2],hh[3],hh[4],hh[5],hh[6],hh[7]};
  short8 vl = {ll[0],ll[1],ll[2],ll[3],ll[4],ll[5],ll[6],ll[7]};
  *(short8*)(a.hi[seg] + off) = vh;
  *(short8*)(a.lo[seg] + off) = vl;
}

// ---------------- bf16x3 MFMA GEMM, LDS double-buffered ----------------
// C = X @ W^T + bias. X:(MPAD,K) bf16 hi/lo, W:(N,K) bf16 hi/lo.
// Block 256 thr = 4 waves; tile 64x64; BK=32; wave -> 32x32 (2x2 of 16x16).
// Epilogue options: fp32 C, bf16 hi/lo split C, sigmoid(gate*c)*c.
struct GemmZ {
  const short* Ah[3]; const short* Al[3];
  const short* Bh[3]; const short* Bl[3];
  const float* bias[3];
  float* Cf[3]; short* Ch[3]; short* Cl[3];
  const short* Gh; const short* Gl;   // gate hi/lo (q_sig), null if ungated
};

__global__ __launch_bounds__(256)
void mfma_gemm(GemmZ p, int M, int N, int K) {
  const int z = blockIdx.z;
  const short* __restrict__ Ah = p.Ah[z];
  const short* __restrict__ Al = p.Al[z];
  const short* __restrict__ Bh = p.Bh[z];
  const short* __restrict__ Bl = p.Bl[z];

  __shared__ short lds[2][4][64 * 32];   // [buf][Ah,Al,Bh,Bl][row*32+k] = 32 KB

  const int t = threadIdx.x;
  const int w = t >> 6, ln = t & 63;
  const int lm = ln & 15, quad = ln >> 4;
  const int m0 = blockIdx.x * 64, n0 = blockIdx.y * 64;

  // staging map: thread -> (row srow of 64, 8-short chunk skoff); lane-linear in LDS
  const int srow = (w << 4) + (ln >> 2);
  const int skoff = (ln & 3) << 3;
  const size_t aoff = (size_t)(m0 + srow) * K + skoff;
  const size_t boff = (size_t)(n0 + srow) * K + skoff;
  const int sidx = srow * 32 + skoff;

  const int mh = (w & 1) << 5, nh = (w >> 1) << 5;

  float4v acc[2][2] = {{{0.f,0.f,0.f,0.f},{0.f,0.f,0.f,0.f}},
                       {{0.f,0.f,0.f,0.f},{0.f,0.f,0.f,0.f}}};

  short8 rAh = *(const short8*)(Ah + aoff);
  short8 rAl = *(const short8*)(Al + aoff);
  short8 rBh = *(const short8*)(Bh + boff);
  short8 rBl = *(const short8*)(Bl + boff);

  const int T = K >> 5;   // 16
  for (int kt = 0; kt < T; ++kt) {
    const int buf = kt & 1;
    *(short8*)&lds[buf][0][sidx] = rAh;
    *(short8*)&lds[buf][1][sidx] = rAl;
    *(short8*)&lds[buf][2][sidx] = rBh;
    *(short8*)&lds[buf][3][sidx] = rBl;
    __syncthreads();
    if (kt + 1 < T) {      // register prefetch overlaps compute below
      const size_t ka = aoff + (size_t)(kt + 1) * 32;
      const size_t kb = boff + (size_t)(kt + 1) * 32;
      rAh = *(const short8*)(Ah + ka);
      rAl = *(const short8*)(Al + ka);
      rBh = *(const short8*)(Bh + kb);
      rBl = *(const short8*)(Bl + kb);
    }
    short8 fah[2], fal[2], fbh[2], fbl[2];
    #pragma unroll
    for (int i = 0; i < 2; ++i) {
      const int ar = (mh + (i << 4) + lm) * 32 + (quad << 3);
      const int br = (nh + (i << 4) + lm) * 32 + (quad << 3);
      fah[i] = *(const short8*)&lds[buf][0][ar];
      fal[i] = *(const short8*)&lds[buf][1][ar];
      fbh[i] = *(const short8*)&lds[buf][2][br];
      fbl[i] = *(const short8*)&lds[buf][3][br];
    }
    #pragma unroll
    for (int mi = 0; mi < 2; ++mi)
      #pragma unroll
      for (int ni = 0; ni < 2; ++ni) {
        acc[mi][ni] = __builtin_amdgcn_mfma_f32_16x16x32_bf16(fah[mi], fbh[ni], acc[mi][ni], 0,0,0);
        acc[mi][ni] = __builtin_amdgcn_mfma_f32_16x16x32_bf16(fah[mi], fbl[ni], acc[mi][ni], 0,0,0);
        acc[mi][ni] = __builtin_amdgcn_mfma_f32_16x16x32_bf16(fal[mi], fbh[ni], acc[mi][ni], 0,0,0);
      }
  }

  const float* bias = p.bias[z];
  float* Cf = p.Cf[z]; short* Ch = p.Ch[z]; short* Cl = p.Cl[z];
  #pragma unroll
  for (int mi = 0; mi < 2; ++mi)
    #pragma unroll
    for (int ni = 0; ni < 2; ++ni) {
      const int n = n0 + nh + (ni << 4) + lm;
      const float bv = bias[n];
      #pragma unroll
      for (int r = 0; r < 4; ++r) {
        const int m = m0 + mh + (mi << 4) + (quad << 2) + r;
        if (m < M) {
          float c = acc[mi][ni][r] + bv;
          if (p.Gh) {
            float qg = b2f(p.Gh[(size_t)m * N + n]) + b2f(p.Gl[(size_t)m * N + n]);
            c = __fdividef(c, 1.f + __expf(-qg * c));   // sigmoid(qg*c)*c
          }
          if (Cf) Cf[(size_t)m * N + n] = c;
          if (Ch) {
            short hi = f2b(c);
            Ch[(size_t)m * N + n] = hi;
            Cl[(size_t)m * N + n] = f2b(c - b2f(hi));
          }
        }
      }
    }
}

// ---------------- scores via MFMA: S[b,h,q,k] = sum_d qs*kp (bf16x3) --------
// grid (13 q-tiles, 32 bh), block 256. A,B direct from global (L2-resident).
__global__ __launch_bounds__(256)
void scores_mfma(const short* __restrict__ qsh, const short* __restrict__ qsl,
                 const short* __restrict__ ksh, const short* __restrict__ ksl,
                 float* __restrict__ sbuf) {
  const int q0 = blockIdx.x * 16;
  const int bh = blockIdx.y;
  const int b = bh >> 3, h = bh & 7;
  const int w = threadIdx.x >> 6, ln = threadIdx.x & 63;
  const int lm = ln & 15, quad = ln >> 4;

  const size_t abase = ((size_t)(b * NQ) + q0 + lm) * HD + h * DK + (quad << 3);
  short8 ah0 = *(const short8*)(qsh + abase);
  short8 ah1 = *(const short8*)(qsh + abase + 32);
  short8 al0 = *(const short8*)(qsl + abase);
  short8 al1 = *(const short8*)(qsl + abase + 32);

  for (int nt = w; nt < 13; nt += 4) {
    const size_t bbase = ((size_t)(b * NQ) + nt * 16 + lm) * HD + h * DK + (quad << 3);
    short8 bh0 = *(const short8*)(ksh + bbase);
    short8 bh1 = *(const short8*)(ksh + bbase + 32);
    short8 bl0 = *(const short8*)(ksl + bbase);
    short8 bl1 = *(const short8*)(ksl + bbase + 32);
    float4v acc = {0.f, 0.f, 0.f, 0.f};
    acc = __builtin_amdgcn_mfma_f32_16x16x32_bf16(ah0, bh0, acc, 0,0,0);
    acc = __builtin_amdgcn_mfma_f32_16x16x32_bf16(ah1, bh1, acc, 0,0,0);
    acc = __builtin_amdgcn_mfma_f32_16x16x32_bf16(ah0, bl0, acc, 0,0,0);
    acc = __builtin_amdgcn_mfma_f32_16x16x32_bf16(ah1, bl1, acc, 0,0,0);
    acc = __builtin_amdgcn_mfma_f32_16x16x32_bf16(al0, bh0, acc, 0,0,0);
    acc = __builtin_amdgcn_mfma_f32_16x16x32_bf16(al1, bh1, acc, 0,0,0);
    const int kcol = nt * 16 + lm;
    if (kcol < NQ) {
      #pragma unroll
      for (int r = 0; r < 4; ++r) {
        const int q = q0 + (quad << 2) + r;
        if (q < NQ)
          sbuf[((size_t)(b * NH + h) * NQ + q) * NQ + kcol] = acc[r];
      }
    }
  }
}

// ---------------- softmax (in place): p = softmax_k(S * scale) ----------------
__global__ __launch_bounds__(256)
void softmax_kernel(float* __restrict__ pbuf, const float* __restrict__ scg) {
  const int q = blockIdx.x, h = blockIdx.y, b = blockIdx.z;
  const int t = threadIdx.x;
  const size_t row = ((size_t)(b * NH + h) * NQ + q) * NQ;
  __shared__ float red[8];

  float att = -1e30f;
  if (t < NQ)
    att = pbuf[row + t] * scg[((size_t)h * NQ + q) * NQ + t];
  float m = att;
  #pragma unroll
  for (int off = 32; off; off >>= 1) m = fmaxf(m, __shfl_xor(m, off, 64));
  if ((t & 63) == 0) red[t >> 6] = m;
  __syncthreads();
  m = fmaxf(fmaxf(red[0], red[1]), fmaxf(red[2], red[3]));
  const float e = (t < NQ) ? __expf(att - m) : 0.f;
  float s = e;
  #pragma unroll
  for (int off = 32; off; off >>= 1) s += __shfl_xor(s, off, 64);
  if ((t & 63) == 0) red[4 + (t >> 6)] = s;
  __syncthreads();
  s = red[4] + red[5] + red[6] + red[7];
  if (t < NQ) pbuf[row + t] = e * __fdividef(1.f, s);
}

// ---------------- gated PV: QB=2, k-split 2, partials to part0/part1 --------
__global__ __launch_bounds__(512)
void pv_kernel(const short* __restrict__ qsh, const short* __restrict__ qsl,
               const float* __restrict__ kpg, const float* __restrict__ vpg,
               const float* __restrict__ pbuf,
               float* __restrict__ part0, float* __restrict__ part1) {
  const int b  = blockIdx.y;
  const int x  = blockIdx.x;        // 196 = 98 q-pairs x 2 k-halves
  const int ks = x & 1;
  const int q0 = (x >> 1) * 2;
  const int hd = threadIdx.x;
  const int h  = hd >> 6;

  const float LOG2E = 1.4426950408889634f;
  const size_t r0 = ((size_t)(b * NQ) + q0) * HD + hd;
  const float nqs0 = -(b2f(qsh[r0]) + b2f(qsl[r0])) * LOG2E;
  const float nqs1 = -(b2f(qsh[r0 + HD]) + b2f(qsl[r0 + HD])) * LOG2E;

  const float* kp = kpg + (size_t)b * NQ * HD + hd;
  const float* vp = vpg + (size_t)b * NQ * HD + hd;
  const float* p0 = pbuf + ((size_t)(b * NH + h) * NQ + q0) * NQ;
  const float* p1 = p0 + NQ;

  float acc0 = 0.f, acc1 = 0.f;
  const int kbeg = ks * 98, kend = kbeg + 98;
  #pragma unroll 2
  for (int k = kbeg; k < kend; ++k) {
    float kv = kp[(size_t)k * HD];
    float vv = vp[(size_t)k * HD];
    float e0 = exp2f(nqs0 * kv);
    float e1 = exp2f(nqs1 * kv);
    float g0 = __fdividef(vv, 1.f + e0);   // sigmoid(qs0*kv)*vv
    float g1 = __fdividef(vv, 1.f + e1);
    acc0 += p0[k] * g0;
    acc1 += p1[k] * g1;
  }
  float* dst = (ks ? part1 : part0) + r0;
  dst[0]  = acc0;
  dst[HD] = acc1;
}

// ---------------- image = part0 + part1 -> bf16 hi/lo ----------------
__global__ __launch_bounds__(256)
void img_split(const float* __restrict__ p0, const float* __restrict__ p1,
               short* __restrict__ ih, short* __restrict__ il) {
  const size_t off = (size_t)blockIdx.x * 2048 + (size_t)threadIdx.x * 8;
  float4 a0 = *(const float4*)(p0 + off);
  float4 a1 = *(const float4*)(p0 + off + 4);
  float4 b0 = *(const float4*)(p1 + off);
  float4 b1 = *(const float4*)(p1 + off + 4);
  float x[8] = {a0.x+b0.x, a0.y+b0.y, a0.z+b0.z, a0.w+b0.w,
                a1.x+b1.x, a1.y+b1.y, a1.z+b1.z, a1.w+b1.w};
  short hh[8], ll[8];
  #pragma unroll
  for (int i = 0; i < 8; ++i) {
    hh[i] = f2b(x[i]);
    ll[i] = f2b(x[i] - b2f(hh[i]));
  }
  short8 vh = {hh[0],hh[1],hh[2],hh[3],hh[4],hh[5],hh[6],hh[7]};
  short8 vl = {ll[0],ll[1],ll[2],ll[3],ll[4],ll[5],ll[6],ll[7]};
  *(short8*)(ih + off) = vh;
  *(short8*)(il + off) = vl;
}

extern "C" void kernel_launch(void* const* d_in, const int* in_sizes, int n_in,
                              void* d_out, int out_size, void* d_ws, size_t ws_size,
                              hipStream_t stream) {
  const float* queries = (const float*)d_in[0];
  const float* keys    = (const float*)d_in[1];
  const float* values  = (const float*)d_in[2];
  const float* Wq = (const float*)d_in[3];
  const float* bq = (const float*)d_in[4];
  const float* Wk = (const float*)d_in[5];
  const float* bk = (const float*)d_in[6];
  const float* Wv = (const float*)d_in[7];
  const float* bv = (const float*)d_in[8];
  const float* Wo = (const float*)d_in[9];
  const float* bo = (const float*)d_in[10];
  const float* scale = (const float*)d_in[11];

  // ---- workspace layout (bytes) ----
  char* base = (char*)d_ws;
  const size_t FB = sizeof(float);
  const size_t NELF  = (size_t)MROWS * HD;   // 401408 (fp32 arrays, 784 rows)
  const size_t NELPS = (size_t)MPAD * HD;    // 425984 (bf16 arrays, 832 rows)
  const size_t WEL   = (size_t)HD * HD;      // 262144

  size_t o = 0;
  float* k_p  = (float*)(base + o); o += NELF * FB;
  float* v_p  = (float*)(base + o); o += NELF * FB;
  float* pbuf = (float*)(base + o); o += (size_t)BATCH * NH * NQ * NQ * FB;  // S, then p in place
  short* Wqh = (short*)(base + o); o += WEL * 2;
  short* Wql = (short*)(base + o); o += WEL * 2;
  short* Wkh = (short*)(base + o); o += WEL * 2;
  short* Wkl = (short*)(base + o); o += WEL * 2;
  short* Wvh = (short*)(base + o); o += WEL * 2;
  short* Wvl = (short*)(base + o); o += WEL * 2;
  short* Woh = (short*)(base + o); o += WEL * 2;
  short* Wol = (short*)(base + o); o += WEL * 2;
  short* qsh = (short*)(base + o); o += NELPS * 2;   // split of q_sig
  short* qsl = (short*)(base + o); o += NELPS * 2;
  short* ksh = (short*)(base + o); o += NELPS * 2;   // split of k_p
  short* ksl = (short*)(base + o); o += NELPS * 2;
  // region A: input splits (dead after proj gemm), later reused
  char* regA = base + o;
  short* qh = (short*)(regA);
  short* ql = qh + NELPS; short* kh = ql + NELPS; short* kl = kh + NELPS;
  short* vh = kl + NELPS; short* vl = vh + NELPS;          // 6*NELPS shorts
  // aliases (written after proj gemm completes, stream-ordered):
  float* part0 = (float*)(regA);                            // 401408 f
  float* part1 = part0 + NELF;                              // 401408 f
  short* imgh  = (short*)(part1 + NELF);                    // 425984 sh
  short* imgl  = imgh + NELPS;                              // 425984 sh

  // 1) split inputs to bf16 hi/lo
  SplitArgs sa;
  sa.src[0] = queries; sa.hi[0] = qh;  sa.lo[0] = ql;
  sa.src[1] = keys;    sa.hi[1] = kh;  sa.lo[1] = kl;
  sa.src[2] = values;  sa.hi[2] = vh;  sa.lo[2] = vl;
  sa.src[3] = Wq;      sa.hi[3] = Wqh; sa.lo[3] = Wql;
  sa.src[4] = Wk;      sa.hi[4] = Wkh; sa.lo[4] = Wkl;
  sa.src[5] = Wv;      sa.hi[5] = Wvh; sa.lo[5] = Wvl;
  sa.src[6] = Wo;      sa.hi[6] = Woh; sa.lo[6] = Wol;
  split_kernel<<<1100, 256, 0, stream>>>(sa);

  // 2) projections: z0 q_sig (split only), z1 k_p (fp32 + split), z2 v_p (fp32)
  GemmZ gp;
  gp.Ah[0]=qh; gp.Al[0]=ql; gp.Bh[0]=Wqh; gp.Bl[0]=Wql; gp.bias[0]=bq;
  gp.Cf[0]=nullptr; gp.Ch[0]=qsh; gp.Cl[0]=qsl;
  gp.Ah[1]=kh; gp.Al[1]=kl; gp.Bh[1]=Wkh; gp.Bl[1]=Wkl; gp.bias[1]=bk;
  gp.Cf[1]=k_p; gp.Ch[1]=ksh; gp.Cl[1]=ksl;
  gp.Ah[2]=vh; gp.Al[2]=vl; gp.Bh[2]=Wvh; gp.Bl[2]=Wvl; gp.bias[2]=bv;
  gp.Cf[2]=v_p; gp.Ch[2]=nullptr; gp.Cl[2]=nullptr;
  gp.Gh = nullptr; gp.Gl = nullptr;
  mfma_gemm<<<dim3(MPAD/64, HD/64, 3), 256, 0, stream>>>(gp, MROWS, HD, HD);

  // 3) scores (MFMA) -> pbuf holds S
  scores_mfma<<<dim3(13, NH*BATCH), 256, 0, stream>>>(qsh, qsl, ksh, ksl, pbuf);

  // 4) softmax in place: pbuf holds p
  softmax_kernel<<<dim3(NQ, NH, BATCH), 256, 0, stream>>>(pbuf, scale);

  // 5) gated PV partials
  pv_kernel<<<dim3(196, BATCH), 512, 0, stream>>>(qsh, qsl, k_p, v_p, pbuf, part0, part1);

  // 6) image = part0+part1 -> bf16 hi/lo
  img_split<<<MROWS*HD/2048, 256, 0, stream>>>(part0, part1, imgh, imgl);

  // 7) out = image @ Wo^T + bo, gated by q_sig
  GemmZ go;
  go.Ah[0]=imgh; go.Al[0]=imgl; go.Bh[0]=Woh; go.Bl[0]=Wol; go.bias[0]=bo;
  go.Cf[0]=(float*)d_out; go.Ch[0]=nullptr; go.Cl[0]=nullptr;
  for (int i = 1; i < 3; ++i) {
    go.Ah[i]=nullptr; go.Al[i]=nullptr; go.Bh[i]=nullptr; go.Bl[i]=nullptr;
    go.bias[i]=nullptr; go.Cf[i]=nullptr; go.Ch[i]=nullptr; go.Cl[i]=nullptr;
  }
  go.Gh = qsh; go.Gl = qsl;
  mfma_gemm<<<dim3(MPAD/64, HD/64, 1), 256, 0, stream>>>(go, MROWS, HD, HD);
}

// Round 5
// 148.472 us; speedup vs baseline: 1.6329x; 1.2880x over previous
//
#include <hip/hip_runtime.h>
#include <hip/hip_bf16.h>
#include <math.h>

#define NQ 196
#define BATCH 4
#define HD 512            // H * D_K == D_MODEL
#define NH 8
#define DK 64
#define MROWS 784         // BATCH*NQ
#define MPAD 832          // buffer row allocation (slack for OOB-safe tile reads)

typedef __attribute__((ext_vector_type(8))) short short8;
typedef __attribute__((ext_vector_type(4))) float float4v;

__device__ __forceinline__ float b2f(short s) {
  return __uint_as_float(((unsigned)(unsigned short)s) << 16);
}
__device__ __forceinline__ short f2b(float x) {
  return __builtin_bit_cast(short, __float2bfloat16(x));
}
// raw transcendentals (inputs are O(1): no range fixup needed)
__device__ __forceinline__ float fexp2(float x) {
  float r; asm("v_exp_f32 %0, %1" : "=v"(r) : "v"(x)); return r;
}
__device__ __forceinline__ float frcp(float x) {
  float r; asm("v_rcp_f32 %0, %1" : "=v"(r) : "v"(x)); return r;
}

// ---------------- split: fp32 -> bf16 hi/lo pair ----------------
struct SplitArgs {
  const float* src[7];
  short* hi[7];
  short* lo[7];
};

__global__ __launch_bounds__(256)
void split_kernel(SplitArgs a) {
  const int blk = blockIdx.x;
  int seg, base;
  if (blk < 588) { seg = blk / 196; base = seg * 196; }
  else           { seg = 3 + (blk - 588) / 128; base = 588 + (seg - 3) * 128; }
  const size_t off = (size_t)(blk - base) * 2048 + (size_t)threadIdx.x * 8;
  const float* src = a.src[seg] + off;
  float4 v0 = *(const float4*)(src);
  float4 v1 = *(const float4*)(src + 4);
  float x[8] = {v0.x, v0.y, v0.z, v0.w, v1.x, v1.y, v1.z, v1.w};
  short hh[8], ll[8];
  #pragma unroll
  for (int i = 0; i < 8; ++i) {
    hh[i] = f2b(x[i]);
    ll[i] = f2b(x[i] - b2f(hh[i]));
  }
  short8 vh = {hh[0],hh[1],hh[2],hh[3],hh[4],hh[5],hh[6],hh[7]};
  short8 vl = {ll[0],ll[1],ll[2],ll[3],ll[4],ll[5],ll[6],ll[7]};
  *(short8*)(a.hi[seg] + off) = vh;
  *(short8*)(a.lo[seg] + off) = vl;
}

// ---------------- bf16x3 MFMA GEMM, tile 32(M)x64(N), BK=32 ----------------
struct GemmZ {
  const short* Ah[3]; const short* Al[3];
  const short* Bh[3]; const short* Bl[3];
  const float* bias[3];
  float* Cf[3]; short* Ch[3]; short* Cl[3];
  const short* Gh; const short* Gl;   // gate hi/lo (q_sig), null if ungated
};

__global__ __launch_bounds__(256)
void mfma_gemm(GemmZ p, int M, int N, int K) {
  const int z = blockIdx.z;
  const short* __restrict__ Ah = p.Ah[z];
  const short* __restrict__ Al = p.Al[z];
  const short* __restrict__ Bh = p.Bh[z];
  const short* __restrict__ Bl = p.Bl[z];

  __shared__ short ldsA[2][2][32 * 32];   // [buf][hi/lo][row*32+k]
  __shared__ short ldsB[2][2][64 * 32];

  const int t = threadIdx.x;
  const int w = t >> 6, ln = t & 63;
  const int lm = ln & 15, quad = ln >> 4;
  const int m0 = blockIdx.x * 32, n0 = blockIdx.y * 64;

  // staging maps
  const int aArr = t >> 7;               // 0:hi 1:lo
  const int aIdx = t & 127;
  const int aRow = aIdx >> 2, aK = (aIdx & 3) << 3;
  const int bRow = t >> 2,    bK = (t & 3) << 3;
  const short* __restrict__ Asrc = aArr ? Al : Ah;
  const size_t aoff = (size_t)(m0 + aRow) * K + aK;
  const size_t boff = (size_t)(n0 + bRow) * K + bK;

  const int wm = (w & 1) << 4, wn = (w >> 1) << 5;

  float4v acc[2] = {{0.f,0.f,0.f,0.f},{0.f,0.f,0.f,0.f}};

  short8 rA  = *(const short8*)(Asrc + aoff);
  short8 rBh = *(const short8*)(Bh + boff);
  short8 rBl = *(const short8*)(Bl + boff);

  const int T = K >> 5;   // 16
  for (int kt = 0; kt < T; ++kt) {
    const int buf = kt & 1;
    *(short8*)&ldsA[buf][aArr][aRow * 32 + aK] = rA;
    *(short8*)&ldsB[buf][0][bRow * 32 + bK]    = rBh;
    *(short8*)&ldsB[buf][1][bRow * 32 + bK]    = rBl;
    __syncthreads();
    if (kt + 1 < T) {   // register prefetch overlaps compute
      rA  = *(const short8*)(Asrc + aoff + (size_t)(kt + 1) * 32);
      rBh = *(const short8*)(Bh + boff + (size_t)(kt + 1) * 32);
      rBl = *(const short8*)(Bl + boff + (size_t)(kt + 1) * 32);
    }
    short8 fah = *(const short8*)&ldsA[buf][0][(wm + lm) * 32 + (quad << 3)];
    short8 fal = *(const short8*)&ldsA[buf][1][(wm + lm) * 32 + (quad << 3)];
    #pragma unroll
    for (int ni = 0; ni < 2; ++ni) {
      short8 fbh = *(const short8*)&ldsB[buf][0][(wn + (ni << 4) + lm) * 32 + (quad << 3)];
      short8 fbl = *(const short8*)&ldsB[buf][1][(wn + (ni << 4) + lm) * 32 + (quad << 3)];
      acc[ni] = __builtin_amdgcn_mfma_f32_16x16x32_bf16(fah, fbh, acc[ni], 0,0,0);
      acc[ni] = __builtin_amdgcn_mfma_f32_16x16x32_bf16(fah, fbl, acc[ni], 0,0,0);
      acc[ni] = __builtin_amdgcn_mfma_f32_16x16x32_bf16(fal, fbh, acc[ni], 0,0,0);
    }
  }

  const float* bias = p.bias[z];
  float* Cf = p.Cf[z]; short* Ch = p.Ch[z]; short* Cl = p.Cl[z];
  #pragma unroll
  for (int ni = 0; ni < 2; ++ni) {
    const int n = n0 + wn + (ni << 4) + lm;
    const float bv = bias[n];
    #pragma unroll
    for (int r = 0; r < 4; ++r) {
      const int m = m0 + wm + (quad << 2) + r;
      if (m < M) {
        float c = acc[ni][r] + bv;
        if (p.Gh) {
          float qg = b2f(p.Gh[(size_t)m * N + n]) + b2f(p.Gl[(size_t)m * N + n]);
          c = __fdividef(c, 1.f + __expf(-qg * c));   // sigmoid(qg*c)*c
        }
        if (Cf) Cf[(size_t)m * N + n] = c;
        if (Ch) {
          short hi = f2b(c);
          Ch[(size_t)m * N + n] = hi;
          Cl[(size_t)m * N + n] = f2b(c - b2f(hi));
        }
      }
    }
  }
}

// -------- fused scores (MFMA) + softmax -> p, S never leaves LDS --------
// grid (13 q-tiles, 32 bh), 256 threads.
__global__ __launch_bounds__(256)
void scores_softmax(const short* __restrict__ qsh, const short* __restrict__ qsl,
                    const short* __restrict__ ksh, const short* __restrict__ ksl,
                    const float* __restrict__ scg, float* __restrict__ pbuf) {
  const int q0 = blockIdx.x * 16;
  const int bh = blockIdx.y;
  const int b = bh >> 3, h = bh & 7;
  const int w = threadIdx.x >> 6, ln = threadIdx.x & 63;
  const int lm = ln & 15, quad = ln >> 4;
  const float L2E = 1.4426950408889634f;

  __shared__ float S[16][210];   // row stride 210: 2-way max bank aliasing (free)

  const size_t abase = ((size_t)(b * NQ) + q0 + lm) * HD + h * DK + (quad << 3);
  short8 ah0 = *(const short8*)(qsh + abase);
  short8 ah1 = *(const short8*)(qsh + abase + 32);
  short8 al0 = *(const short8*)(qsl + abase);
  short8 al1 = *(const short8*)(qsl + abase + 32);

  for (int nt = w; nt < 13; nt += 4) {
    const size_t bbase = ((size_t)(b * NQ) + nt * 16 + lm) * HD + h * DK + (quad << 3);
    short8 bh0 = *(const short8*)(ksh + bbase);
    short8 bh1 = *(const short8*)(ksh + bbase + 32);
    short8 bl0 = *(const short8*)(ksl + bbase);
    short8 bl1 = *(const short8*)(ksl + bbase + 32);
    float4v acc = {0.f, 0.f, 0.f, 0.f};
    acc = __builtin_amdgcn_mfma_f32_16x16x32_bf16(ah0, bh0, acc, 0,0,0);
    acc = __builtin_amdgcn_mfma_f32_16x16x32_bf16(ah1, bh1, acc, 0,0,0);
    acc = __builtin_amdgcn_mfma_f32_16x16x32_bf16(ah0, bl0, acc, 0,0,0);
    acc = __builtin_amdgcn_mfma_f32_16x16x32_bf16(ah1, bl1, acc, 0,0,0);
    acc = __builtin_amdgcn_mfma_f32_16x16x32_bf16(al0, bh0, acc, 0,0,0);
    acc = __builtin_amdgcn_mfma_f32_16x16x32_bf16(al1, bh1, acc, 0,0,0);
    #pragma unroll
    for (int r = 0; r < 4; ++r)
      S[(quad << 2) + r][nt * 16 + lm] = acc[r];
  }
  __syncthreads();

  // softmax: wave w handles rows 4w..4w+3 (base-2 exp of L2E-scaled logits)
  for (int i = 0; i < 4; ++i) {
    const int rr = (w << 2) + i;
    const int q = q0 + rr;
    const bool qok = q < NQ;
    const float* srow = scg + ((size_t)h * NQ + (qok ? q : 0)) * NQ;
    float att[4];
    #pragma unroll
    for (int j = 0; j < 4; ++j) {
      const int c = ln + (j << 6);
      att[j] = -1e30f;
      if (c < NQ) att[j] = S[rr][c] * srow[c] * L2E;
    }
    float m = fmaxf(fmaxf(att[0], att[1]), fmaxf(att[2], att[3]));
    #pragma unroll
    for (int off = 32; off; off >>= 1) m = fmaxf(m, __shfl_xor(m, off, 64));
    float e[4], s = 0.f;
    #pragma unroll
    for (int j = 0; j < 4; ++j) { e[j] = fexp2(att[j] - m); s += e[j]; }
    #pragma unroll
    for (int off = 32; off; off >>= 1) s += __shfl_xor(s, off, 64);
    const float rinv = __fdividef(1.f, s);
    if (qok) {
      float* prow = pbuf + (((size_t)(b * NH + h) * NQ) + q) * NQ;
      #pragma unroll
      for (int j = 0; j < 4; ++j) {
        const int c = ln + (j << 6);
        if (c < NQ) prow[c] = e[j] * rinv;
      }
    }
  }
}

// ---------------- gated PV: QB=4, k-split 4, raw trans ----------------
__global__ __launch_bounds__(512)
void pv_kernel(const short* __restrict__ qsh, const short* __restrict__ qsl,
               const float* __restrict__ kpg, const float* __restrict__ vpg,
               const float* __restrict__ pbuf, float* __restrict__ part) {
  const int b  = blockIdx.y;
  const int x  = blockIdx.x;        // 49 q-groups x 4 k-slices
  const int ks = x & 3;
  const int q0 = (x >> 2) << 2;
  const int hd = threadIdx.x;
  const int h  = hd >> 6;
  const float LOG2E = 1.4426950408889634f;

  const size_t r0 = ((size_t)(b * NQ) + q0) * HD + hd;
  float nqs[4];
  #pragma unroll
  for (int qi = 0; qi < 4; ++qi) {
    const size_t rr = r0 + (size_t)qi * HD;
    nqs[qi] = -(b2f(qsh[rr]) + b2f(qsl[rr])) * LOG2E;
  }
  const float* kp = kpg + (size_t)b * NQ * HD + hd;
  const float* vp = vpg + (size_t)b * NQ * HD + hd;
  const float* pr = pbuf + ((size_t)(b * NH + h) * NQ + q0) * NQ;

  float acc[4] = {0.f, 0.f, 0.f, 0.f};
  const int kbeg = ks * 49;
  for (int k = kbeg; k < kbeg + 49; ++k) {
    const float kv = kp[(size_t)k * HD];
    const float vv = vp[(size_t)k * HD];
    #pragma unroll
    for (int qi = 0; qi < 4; ++qi) {
      const float e = fexp2(nqs[qi] * kv);          // e^(-qs*kv)
      const float g = vv * frcp(1.f + e);           // sigmoid(qs*kv)*vv
      acc[qi] += pr[(size_t)qi * NQ + k] * g;
    }
  }
  float* dst = part + (size_t)ks * ((size_t)MROWS * HD) + r0;
  #pragma unroll
  for (int qi = 0; qi < 4; ++qi) dst[(size_t)qi * HD] = acc[qi];
}

// ---------------- image = sum of 4 partials -> bf16 hi/lo ----------------
__global__ __launch_bounds__(256)
void img_split(const float* __restrict__ part, short* __restrict__ ih,
               short* __restrict__ il) {
  const size_t NELF = (size_t)MROWS * HD;
  const size_t off = (size_t)blockIdx.x * 2048 + (size_t)threadIdx.x * 8;
  float x[8];
  #pragma unroll
  for (int i = 0; i < 8; i += 4) {
    float4 s0 = *(const float4*)(part + off + i);
    float4 s1 = *(const float4*)(part + NELF + off + i);
    float4 s2 = *(const float4*)(part + 2 * NELF + off + i);
    float4 s3 = *(const float4*)(part + 3 * NELF + off + i);
    x[i+0] = s0.x + s1.x + s2.x + s3.x;
    x[i+1] = s0.y + s1.y + s2.y + s3.y;
    x[i+2] = s0.z + s1.z + s2.z + s3.z;
    x[i+3] = s0.w + s1.w + s2.w + s3.w;
  }
  short hh[8], ll[8];
  #pragma unroll
  for (int i = 0; i < 8; ++i) {
    hh[i] = f2b(x[i]);
    ll[i] = f2b(x[i] - b2f(hh[i]));
  }
  short8 vh = {hh[0],hh[1],hh[2],hh[3],hh[4],hh[5],hh[6],hh[7]};
  short8 vl = {ll[0],ll[1],ll[2],ll[3],ll[4],ll[5],ll[6],ll[7]};
  *(short8*)(ih + off) = vh;
  *(short8*)(il + off) = vl;
}

extern "C" void kernel_launch(void* const* d_in, const int* in_sizes, int n_in,
                              void* d_out, int out_size, void* d_ws, size_t ws_size,
                              hipStream_t stream) {
  const float* queries = (const float*)d_in[0];
  const float* keys    = (const float*)d_in[1];
  const float* values  = (const float*)d_in[2];
  const float* Wq = (const float*)d_in[3];
  const float* bq = (const float*)d_in[4];
  const float* Wk = (const float*)d_in[5];
  const float* bk = (const float*)d_in[6];
  const float* Wv = (const float*)d_in[7];
  const float* bv = (const float*)d_in[8];
  const float* Wo = (const float*)d_in[9];
  const float* bo = (const float*)d_in[10];
  const float* scale = (const float*)d_in[11];

  char* base = (char*)d_ws;
  const size_t FB = sizeof(float);
  const size_t NELF  = (size_t)MROWS * HD;   // 401408
  const size_t NELPS = (size_t)MPAD * HD;    // 425984
  const size_t WEL   = (size_t)HD * HD;      // 262144

  size_t o = 0;
  float* k_p  = (float*)(base + o); o += NELF * FB;
  float* v_p  = (float*)(base + o); o += NELF * FB;
  float* pbuf = (float*)(base + o); o += (size_t)BATCH * NH * NQ * NQ * FB;
  short* Wqh = (short*)(base + o); o += WEL * 2;
  short* Wql = (short*)(base + o); o += WEL * 2;
  short* Wkh = (short*)(base + o); o += WEL * 2;
  short* Wkl = (short*)(base + o); o += WEL * 2;
  short* Wvh = (short*)(base + o); o += WEL * 2;
  short* Wvl = (short*)(base + o); o += WEL * 2;
  short* Woh = (short*)(base + o); o += WEL * 2;
  short* Wol = (short*)(base + o); o += WEL * 2;
  short* qsh = (short*)(base + o); o += NELPS * 2;
  short* qsl = (short*)(base + o); o += NELPS * 2;
  short* ksh = (short*)(base + o); o += NELPS * 2;
  short* ksl = (short*)(base + o); o += NELPS * 2;
  // region A: input splits (dead after proj gemm), later partials + image
  char* regA = base + o;
  short* qh = (short*)(regA);
  short* ql = qh + NELPS; short* kh = ql + NELPS; short* kl = kh + NELPS;
  short* vh = kl + NELPS; short* vl = vh + NELPS;
  float* part  = (float*)(regA);                   // 4*NELF floats
  short* imgh  = (short*)(part + 4 * NELF);        // NELPS shorts
  short* imgl  = imgh + NELPS;

  // 1) split inputs to bf16 hi/lo
  SplitArgs sa;
  sa.src[0] = queries; sa.hi[0] = qh;  sa.lo[0] = ql;
  sa.src[1] = keys;    sa.hi[1] = kh;  sa.lo[1] = kl;
  sa.src[2] = values;  sa.hi[2] = vh;  sa.lo[2] = vl;
  sa.src[3] = Wq;      sa.hi[3] = Wqh; sa.lo[3] = Wql;
  sa.src[4] = Wk;      sa.hi[4] = Wkh; sa.lo[4] = Wkl;
  sa.src[5] = Wv;      sa.hi[5] = Wvh; sa.lo[5] = Wvl;
  sa.src[6] = Wo;      sa.hi[6] = Woh; sa.lo[6] = Wol;
  split_kernel<<<1100, 256, 0, stream>>>(sa);

  // 2) projections: z0 q_sig (split), z1 k_p (fp32 + split), z2 v_p (fp32)
  GemmZ gp;
  gp.Ah[0]=qh; gp.Al[0]=ql; gp.Bh[0]=Wqh; gp.Bl[0]=Wql; gp.bias[0]=bq;
  gp.Cf[0]=nullptr; gp.Ch[0]=qsh; gp.Cl[0]=qsl;
  gp.Ah[1]=kh; gp.Al[1]=kl; gp.Bh[1]=Wkh; gp.Bl[1]=Wkl; gp.bias[1]=bk;
  gp.Cf[1]=k_p; gp.Ch[1]=ksh; gp.Cl[1]=ksl;
  gp.Ah[2]=vh; gp.Al[2]=vl; gp.Bh[2]=Wvh; gp.Bl[2]=Wvl; gp.bias[2]=bv;
  gp.Cf[2]=v_p; gp.Ch[2]=nullptr; gp.Cl[2]=nullptr;
  gp.Gh = nullptr; gp.Gl = nullptr;
  mfma_gemm<<<dim3(25, HD/64, 3), 256, 0, stream>>>(gp, MROWS, HD, HD);

  // 3) fused scores + softmax -> pbuf
  scores_softmax<<<dim3(13, NH*BATCH), 256, 0, stream>>>(qsh, qsl, ksh, ksl, scale, pbuf);

  // 4) gated PV partials (4 k-slices)
  pv_kernel<<<dim3(196, BATCH), 512, 0, stream>>>(qsh, qsl, k_p, v_p, pbuf, part);

  // 5) image = sum partials -> bf16 hi/lo
  img_split<<<MROWS*HD/2048, 256, 0, stream>>>(part, imgh, imgl);

  // 6) out = image @ Wo^T + bo, gated by q_sig
  GemmZ go;
  go.Ah[0]=imgh; go.Al[0]=imgl; go.Bh[0]=Woh; go.Bl[0]=Wol; go.bias[0]=bo;
  go.Cf[0]=(float*)d_out; go.Ch[0]=nullptr; go.Cl[0]=nullptr;
  for (int i = 1; i < 3; ++i) {
    go.Ah[i]=nullptr; go.Al[i]=nullptr; go.Bh[i]=nullptr; go.Bl[i]=nullptr;
    go.bias[i]=nullptr; go.Cf[i]=nullptr; go.Ch[i]=nullptr; go.Cl[i]=nullptr;
  }
  go.Gh = qsh; go.Gl = qsl;
  mfma_gemm<<<dim3(25, HD/64, 1), 256, 0, stream>>>(go, MROWS, HD, HD);
}

// Round 6
// 144.147 us; speedup vs baseline: 1.6819x; 1.0300x over previous
//
#include <hip/hip_runtime.h>
#include <hip/hip_bf16.h>
#include <math.h>

#define NQ 196
#define BATCH 4
#define HD 512            // H * D_K == D_MODEL
#define NH 8
#define DK 64
#define MROWS 784         // BATCH*NQ
#define MPAD 832          // bf16 ws arrays row slack (tile overhang reads)

typedef __attribute__((ext_vector_type(8))) short short8;
typedef __attribute__((ext_vector_type(4))) short short4v;
typedef __attribute__((ext_vector_type(4))) float float4v;

__device__ __forceinline__ float b2f(short s) {
  return __uint_as_float(((unsigned)(unsigned short)s) << 16);
}
__device__ __forceinline__ short f2b(float x) {
  return __builtin_bit_cast(short, __float2bfloat16(x));
}
// raw transcendentals (inputs are O(1): no range fixup needed)
__device__ __forceinline__ float fexp2(float x) {
  float r; asm("v_exp_f32 %0, %1" : "=v"(r) : "v"(x)); return r;
}
__device__ __forceinline__ float frcp(float x) {
  float r; asm("v_rcp_f32 %0, %1" : "=v"(r) : "v"(x)); return r;
}
__device__ __forceinline__ void cvt4(float4 v, short4v& hi, short4v& lo) {
  float x[4] = {v.x, v.y, v.z, v.w};
  #pragma unroll
  for (int i = 0; i < 4; ++i) {
    hi[i] = f2b(x[i]);
    lo[i] = f2b(x[i] - b2f(hi[i]));
  }
}

// ======== proj GEMM: C = X @ W^T + b, fp32 in, on-the-fly bf16x3 ========
// X:(M,K) fp32, W:(N,K) fp32. Tile 32(M)x64(N), BK=32, 256 thr = 4 waves.
// Epilogue per z: optional fp32 C and/or bf16 hi/lo split C.
struct ProjArgs {
  const float* X[3]; const float* W[3]; const float* bias[3];
  float* Cf[3]; short* Ch[3]; short* Cl[3];
};

__global__ __launch_bounds__(256)
void proj_gemm(ProjArgs p, int M, int N, int K) {
  const int z = blockIdx.z;
  const float* __restrict__ X = p.X[z];
  const float* __restrict__ W = p.W[z];

  __shared__ short ldsA[2][2][32 * 32];   // [buf][hi/lo][row*32+k]
  __shared__ short ldsB[2][2][64 * 32];

  const int t = threadIdx.x;
  const int w = t >> 6, ln = t & 63;
  const int lm = ln & 15, quad = ln >> 4;
  const int m0 = blockIdx.x * 32, n0 = blockIdx.y * 64;

  // staging maps (fp32 sources)
  const int aRow = t >> 3, aK = (t & 7) << 2;   // 32 rows x 32 k, float4
  const int bRow = t >> 2, bK = (t & 3) << 3;   // 64 rows x 32 k, 2x float4
  const int ar = min(m0 + aRow, M - 1);          // row-clamp (tile overhang)
  const float* Ap = X + (size_t)ar * K + aK;
  const float* Bp = W + (size_t)(n0 + bRow) * K + bK;

  const int wm = (w & 1) << 4, wn = (w >> 1) << 5;
  float4v acc[2] = {{0.f,0.f,0.f,0.f},{0.f,0.f,0.f,0.f}};

  float4 ra  = *(const float4*)Ap;
  float4 rb0 = *(const float4*)Bp;
  float4 rb1 = *(const float4*)(Bp + 4);

  const int T = K >> 5;
  for (int kt = 0; kt < T; ++kt) {
    const int buf = kt & 1;
    short4v ahi, alo; cvt4(ra, ahi, alo);
    short4v bh0, bl0, bh1, bl1; cvt4(rb0, bh0, bl0); cvt4(rb1, bh1, bl1);
    *(short4v*)&ldsA[buf][0][aRow * 32 + aK] = ahi;
    *(short4v*)&ldsA[buf][1][aRow * 32 + aK] = alo;
    short8 bh = {bh0[0],bh0[1],bh0[2],bh0[3],bh1[0],bh1[1],bh1[2],bh1[3]};
    short8 bl = {bl0[0],bl0[1],bl0[2],bl0[3],bl1[0],bl1[1],bl1[2],bl1[3]};
    *(short8*)&ldsB[buf][0][bRow * 32 + bK] = bh;
    *(short8*)&ldsB[buf][1][bRow * 32 + bK] = bl;
    __syncthreads();
    if (kt + 1 < T) {   // register prefetch overlaps compute
      ra  = *(const float4*)(Ap + (size_t)(kt + 1) * 32);
      rb0 = *(const float4*)(Bp + (size_t)(kt + 1) * 32);
      rb1 = *(const float4*)(Bp + (size_t)(kt + 1) * 32 + 4);
    }
    short8 fah = *(const short8*)&ldsA[buf][0][(wm + lm) * 32 + (quad << 3)];
    short8 fal = *(const short8*)&ldsA[buf][1][(wm + lm) * 32 + (quad << 3)];
    #pragma unroll
    for (int ni = 0; ni < 2; ++ni) {
      short8 fbh = *(const short8*)&ldsB[buf][0][(wn + (ni << 4) + lm) * 32 + (quad << 3)];
      short8 fbl = *(const short8*)&ldsB[buf][1][(wn + (ni << 4) + lm) * 32 + (quad << 3)];
      acc[ni] = __builtin_amdgcn_mfma_f32_16x16x32_bf16(fah, fbh, acc[ni], 0,0,0);
      acc[ni] = __builtin_amdgcn_mfma_f32_16x16x32_bf16(fah, fbl, acc[ni], 0,0,0);
      acc[ni] = __builtin_amdgcn_mfma_f32_16x16x32_bf16(fal, fbh, acc[ni], 0,0,0);
    }
  }

  const float* bias = p.bias[z];
  float* Cf = p.Cf[z]; short* Ch = p.Ch[z]; short* Cl = p.Cl[z];
  #pragma unroll
  for (int ni = 0; ni < 2; ++ni) {
    const int n = n0 + wn + (ni << 4) + lm;
    const float bv = bias[n];
    #pragma unroll
    for (int r = 0; r < 4; ++r) {
      const int m = m0 + wm + (quad << 2) + r;
      if (m < M) {
        const float c = acc[ni][r] + bv;
        if (Cf) Cf[(size_t)m * N + n] = c;
        if (Ch) {
          const short hi = f2b(c);
          Ch[(size_t)m * N + n] = hi;
          Cl[(size_t)m * N + n] = f2b(c - b2f(hi));
        }
      }
    }
  }
}

// ======== out GEMM: C = (sum of 4 partials) @ Wo^T + bo, gated ========
__global__ __launch_bounds__(256)
void out_gemm(const float* __restrict__ part, const float* __restrict__ W,
              const float* __restrict__ bias, const float* __restrict__ qsg,
              float* __restrict__ C, int M, int N, int K) {
  __shared__ short ldsA[2][2][32 * 32];
  __shared__ short ldsB[2][2][64 * 32];

  const int t = threadIdx.x;
  const int w = t >> 6, ln = t & 63;
  const int lm = ln & 15, quad = ln >> 4;
  const int m0 = blockIdx.x * 32, n0 = blockIdx.y * 64;

  const int aRow = t >> 3, aK = (t & 7) << 2;
  const int bRow = t >> 2, bK = (t & 3) << 3;
  const int ar = min(m0 + aRow, M - 1);
  const size_t NELF = (size_t)MROWS * HD;
  const float* Ap = part + (size_t)ar * K + aK;
  const float* Bp = W + (size_t)(n0 + bRow) * K + bK;

  const int wm = (w & 1) << 4, wn = (w >> 1) << 5;
  float4v acc[2] = {{0.f,0.f,0.f,0.f},{0.f,0.f,0.f,0.f}};

  float4 s0 = *(const float4*)(Ap);
  float4 s1 = *(const float4*)(Ap + NELF);
  float4 s2 = *(const float4*)(Ap + 2 * NELF);
  float4 s3 = *(const float4*)(Ap + 3 * NELF);
  float4 rb0 = *(const float4*)Bp;
  float4 rb1 = *(const float4*)(Bp + 4);

  const int T = K >> 5;
  for (int kt = 0; kt < T; ++kt) {
    const int buf = kt & 1;
    float4 ra = make_float4(s0.x+s1.x+s2.x+s3.x, s0.y+s1.y+s2.y+s3.y,
                            s0.z+s1.z+s2.z+s3.z, s0.w+s1.w+s2.w+s3.w);
    short4v ahi, alo; cvt4(ra, ahi, alo);
    short4v bh0, bl0, bh1, bl1; cvt4(rb0, bh0, bl0); cvt4(rb1, bh1, bl1);
    *(short4v*)&ldsA[buf][0][aRow * 32 + aK] = ahi;
    *(short4v*)&ldsA[buf][1][aRow * 32 + aK] = alo;
    short8 bh = {bh0[0],bh0[1],bh0[2],bh0[3],bh1[0],bh1[1],bh1[2],bh1[3]};
    short8 bl = {bl0[0],bl0[1],bl0[2],bl0[3],bl1[0],bl1[1],bl1[2],bl1[3]};
    *(short8*)&ldsB[buf][0][bRow * 32 + bK] = bh;
    *(short8*)&ldsB[buf][1][bRow * 32 + bK] = bl;
    __syncthreads();
    if (kt + 1 < T) {
      const size_t ko = (size_t)(kt + 1) * 32;
      s0 = *(const float4*)(Ap + ko);
      s1 = *(const float4*)(Ap + NELF + ko);
      s2 = *(const float4*)(Ap + 2 * NELF + ko);
      s3 = *(const float4*)(Ap + 3 * NELF + ko);
      rb0 = *(const float4*)(Bp + ko);
      rb1 = *(const float4*)(Bp + ko + 4);
    }
    short8 fah = *(const short8*)&ldsA[buf][0][(wm + lm) * 32 + (quad << 3)];
    short8 fal = *(const short8*)&ldsA[buf][1][(wm + lm) * 32 + (quad << 3)];
    #pragma unroll
    for (int ni = 0; ni < 2; ++ni) {
      short8 fbh = *(const short8*)&ldsB[buf][0][(wn + (ni << 4) + lm) * 32 + (quad << 3)];
      short8 fbl = *(const short8*)&ldsB[buf][1][(wn + (ni << 4) + lm) * 32 + (quad << 3)];
      acc[ni] = __builtin_amdgcn_mfma_f32_16x16x32_bf16(fah, fbh, acc[ni], 0,0,0);
      acc[ni] = __builtin_amdgcn_mfma_f32_16x16x32_bf16(fah, fbl, acc[ni], 0,0,0);
      acc[ni] = __builtin_amdgcn_mfma_f32_16x16x32_bf16(fal, fbh, acc[ni], 0,0,0);
    }
  }

  #pragma unroll
  for (int ni = 0; ni < 2; ++ni) {
    const int n = n0 + wn + (ni << 4) + lm;
    const float bv = bias[n];
    #pragma unroll
    for (int r = 0; r < 4; ++r) {
      const int m = m0 + wm + (quad << 2) + r;
      if (m < M) {
        float c = acc[ni][r] + bv;
        const float qg = qsg[(size_t)m * N + n];
        c = __fdividef(c, 1.f + __expf(-qg * c));   // sigmoid(qg*c)*c
        C[(size_t)m * N + n] = c;
      }
    }
  }
}

// -------- fused scores (MFMA) + softmax -> p, S never leaves LDS --------
__global__ __launch_bounds__(256)
void scores_softmax(const short* __restrict__ qsh, const short* __restrict__ qsl,
                    const short* __restrict__ ksh, const short* __restrict__ ksl,
                    const float* __restrict__ scg, float* __restrict__ pbuf) {
  const int q0 = blockIdx.x * 16;
  const int bh = blockIdx.y;
  const int b = bh >> 3, h = bh & 7;
  const int w = threadIdx.x >> 6, ln = threadIdx.x & 63;
  const int lm = ln & 15, quad = ln >> 4;
  const float L2E = 1.4426950408889634f;

  __shared__ float S[16][210];   // row stride 210: <=2-way bank aliasing (free)

  const size_t abase = ((size_t)(b * NQ) + q0 + lm) * HD + h * DK + (quad << 3);
  short8 ah0 = *(const short8*)(qsh + abase);
  short8 ah1 = *(const short8*)(qsh + abase + 32);
  short8 al0 = *(const short8*)(qsl + abase);
  short8 al1 = *(const short8*)(qsl + abase + 32);

  for (int nt = w; nt < 13; nt += 4) {
    const size_t bbase = ((size_t)(b * NQ) + nt * 16 + lm) * HD + h * DK + (quad << 3);
    short8 bh0 = *(const short8*)(ksh + bbase);
    short8 bh1 = *(const short8*)(ksh + bbase + 32);
    short8 bl0 = *(const short8*)(ksl + bbase);
    short8 bl1 = *(const short8*)(ksl + bbase + 32);
    float4v acc = {0.f, 0.f, 0.f, 0.f};
    acc = __builtin_amdgcn_mfma_f32_16x16x32_bf16(ah0, bh0, acc, 0,0,0);
    acc = __builtin_amdgcn_mfma_f32_16x16x32_bf16(ah1, bh1, acc, 0,0,0);
    acc = __builtin_amdgcn_mfma_f32_16x16x32_bf16(ah0, bl0, acc, 0,0,0);
    acc = __builtin_amdgcn_mfma_f32_16x16x32_bf16(ah1, bl1, acc, 0,0,0);
    acc = __builtin_amdgcn_mfma_f32_16x16x32_bf16(al0, bh0, acc, 0,0,0);
    acc = __builtin_amdgcn_mfma_f32_16x16x32_bf16(al1, bh1, acc, 0,0,0);
    #pragma unroll
    for (int r = 0; r < 4; ++r)
      S[(quad << 2) + r][nt * 16 + lm] = acc[r];
  }
  __syncthreads();

  for (int i = 0; i < 4; ++i) {
    const int rr = (w << 2) + i;
    const int q = q0 + rr;
    const bool qok = q < NQ;
    const float* srow = scg + ((size_t)h * NQ + (qok ? q : 0)) * NQ;
    float att[4];
    #pragma unroll
    for (int j = 0; j < 4; ++j) {
      const int c = ln + (j << 6);
      att[j] = -1e30f;
      if (c < NQ) att[j] = S[rr][c] * srow[c] * L2E;
    }
    float m = fmaxf(fmaxf(att[0], att[1]), fmaxf(att[2], att[3]));
    #pragma unroll
    for (int off = 32; off; off >>= 1) m = fmaxf(m, __shfl_xor(m, off, 64));
    float e[4], s = 0.f;
    #pragma unroll
    for (int j = 0; j < 4; ++j) { e[j] = fexp2(att[j] - m); s += e[j]; }
    #pragma unroll
    for (int off = 32; off; off >>= 1) s += __shfl_xor(s, off, 64);
    const float rinv = __fdividef(1.f, s);
    if (qok) {
      float* prow = pbuf + (((size_t)(b * NH + h) * NQ) + q) * NQ;
      #pragma unroll
      for (int j = 0; j < 4; ++j) {
        const int c = ln + (j << 6);
        if (c < NQ) prow[c] = e[j] * rinv;
      }
    }
  }
}

// ---------------- gated PV: QB=4, k-split 4, raw trans ----------------
__global__ __launch_bounds__(512)
void pv_kernel(const float* __restrict__ qsg, const float* __restrict__ kpg,
               const float* __restrict__ vpg, const float* __restrict__ pbuf,
               float* __restrict__ part) {
  const int b  = blockIdx.y;
  const int x  = blockIdx.x;        // 49 q-groups x 4 k-slices
  const int ks = x & 3;
  const int q0 = (x >> 2) << 2;
  const int hd = threadIdx.x;
  const int h  = hd >> 6;
  const float LOG2E = 1.4426950408889634f;

  const size_t r0 = ((size_t)(b * NQ) + q0) * HD + hd;
  float nqs[4];
  #pragma unroll
  for (int qi = 0; qi < 4; ++qi)
    nqs[qi] = -qsg[r0 + (size_t)qi * HD] * LOG2E;

  const float* kp = kpg + (size_t)b * NQ * HD + hd;
  const float* vp = vpg + (size_t)b * NQ * HD + hd;
  const float* pr = pbuf + ((size_t)(b * NH + h) * NQ + q0) * NQ;

  float acc[4] = {0.f, 0.f, 0.f, 0.f};
  const int kbeg = ks * 49;
  for (int k = kbeg; k < kbeg + 49; ++k) {
    const float kv = kp[(size_t)k * HD];
    const float vv = vp[(size_t)k * HD];
    #pragma unroll
    for (int qi = 0; qi < 4; ++qi) {
      const float e = fexp2(nqs[qi] * kv);          // e^(-qs*kv)
      const float g = vv * frcp(1.f + e);           // sigmoid(qs*kv)*vv
      acc[qi] += pr[(size_t)qi * NQ + k] * g;
    }
  }
  float* dst = part + (size_t)ks * ((size_t)MROWS * HD) + r0;
  #pragma unroll
  for (int qi = 0; qi < 4; ++qi) dst[(size_t)qi * HD] = acc[qi];
}

extern "C" void kernel_launch(void* const* d_in, const int* in_sizes, int n_in,
                              void* d_out, int out_size, void* d_ws, size_t ws_size,
                              hipStream_t stream) {
  const float* queries = (const float*)d_in[0];
  const float* keys    = (const float*)d_in[1];
  const float* values  = (const float*)d_in[2];
  const float* Wq = (const float*)d_in[3];
  const float* bq = (const float*)d_in[4];
  const float* Wk = (const float*)d_in[5];
  const float* bk = (const float*)d_in[6];
  const float* Wv = (const float*)d_in[7];
  const float* bv = (const float*)d_in[8];
  const float* Wo = (const float*)d_in[9];
  const float* bo = (const float*)d_in[10];
  const float* scale = (const float*)d_in[11];

  char* base = (char*)d_ws;
  const size_t FB = sizeof(float);
  const size_t NELF  = (size_t)MROWS * HD;   // 401408
  const size_t NELPS = (size_t)MPAD * HD;    // 425984

  size_t o = 0;
  float* q_sig = (float*)(base + o); o += NELF * FB;
  float* k_p   = (float*)(base + o); o += NELF * FB;
  float* v_p   = (float*)(base + o); o += NELF * FB;
  float* pbuf  = (float*)(base + o); o += (size_t)BATCH * NH * NQ * NQ * FB;
  short* qsh = (short*)(base + o); o += NELPS * 2;
  short* qsl = (short*)(base + o); o += NELPS * 2;
  short* ksh = (short*)(base + o); o += NELPS * 2;
  short* ksl = (short*)(base + o); o += NELPS * 2;
  float* part = (float*)(base + o); o += 4 * NELF * FB;

  // 1) projections (fp32 in, on-the-fly bf16x3):
  //    z0 q_sig (fp32 + split), z1 k_p (fp32 + split), z2 v_p (fp32)
  ProjArgs gp;
  gp.X[0] = queries; gp.W[0] = Wq; gp.bias[0] = bq;
  gp.Cf[0] = q_sig;  gp.Ch[0] = qsh; gp.Cl[0] = qsl;
  gp.X[1] = keys;    gp.W[1] = Wk; gp.bias[1] = bk;
  gp.Cf[1] = k_p;    gp.Ch[1] = ksh; gp.Cl[1] = ksl;
  gp.X[2] = values;  gp.W[2] = Wv; gp.bias[2] = bv;
  gp.Cf[2] = v_p;    gp.Ch[2] = nullptr; gp.Cl[2] = nullptr;
  proj_gemm<<<dim3(25, HD/64, 3), 256, 0, stream>>>(gp, MROWS, HD, HD);

  // 2) fused scores + softmax -> pbuf
  scores_softmax<<<dim3(13, NH*BATCH), 256, 0, stream>>>(qsh, qsl, ksh, ksl, scale, pbuf);

  // 3) gated PV partials (4 k-slices)
  pv_kernel<<<dim3(196, BATCH), 512, 0, stream>>>(q_sig, k_p, v_p, pbuf, part);

  // 4) out = (sum partials) @ Wo^T + bo, gated by q_sig
  out_gemm<<<dim3(25, HD/64, 1), 256, 0, stream>>>(part, Wo, bo, q_sig,
                                                   (float*)d_out, MROWS, HD, HD);
}